// Round 4
// baseline (183.900 us; speedup 1.0000x reference)
//
#include <hip/hip_runtime.h>
#include <hip/hip_bf16.h>
#include <math.h>
#include <stdint.h>

// Shapes: B=64, T=256, R=49, H=1024
// out = [c_t (B*T*H fp32)] ++ [alpha (B*T*R fp32)]
// ws  = [cv fp32 3136x49][cg fp32 16384x49][alpha16 bf16 16384x64 swizzled]
//       [vT bf16 64x1024x64 swizzled]

typedef __attribute__((ext_vector_type(8))) short bf16x8;
typedef __attribute__((ext_vector_type(4))) short bf16x4;
typedef __attribute__((ext_vector_type(4))) float floatx4;

static __device__ __forceinline__ bf16x8 pack8(float4 a, float4 b) {
    union { __hip_bfloat162 h[4]; bf16x8 v; } u;
    u.h[0] = __float22bfloat162_rn(make_float2(a.x, a.y));
    u.h[1] = __float22bfloat162_rn(make_float2(a.z, a.w));
    u.h[2] = __float22bfloat162_rn(make_float2(b.x, b.y));
    u.h[3] = __float22bfloat162_rn(make_float2(b.z, b.w));
    return u.v;
}

static __device__ __forceinline__ bf16x4 pack4(float4 a) {
    union { __hip_bfloat162 h[2]; bf16x4 v; } u;
    u.h[0] = __float22bfloat162_rn(make_float2(a.x, a.y));
    u.h[1] = __float22bfloat162_rn(make_float2(a.z, a.w));
    return u.v;
}

static __device__ __forceinline__ unsigned short f2bf_bits(float f) {
    union { __hip_bfloat16 h; unsigned short u; } c;
    c.h = __float2bfloat16(f);
    return c.u;
}

// Blocks 0..195: cv = V.Wv^T (M-tile 16); 196..1219: cg = h_t.Wg^T;
// 1220..2243: transpose V -> vT[b][h][r(pad 64)] bf16, octet-swizzled rows.
// GEMM: double-buffered LDS, 2-deep register prefetch, one barrier/iter.
__global__ __launch_bounds__(256) void gemm_mfma_tr(const float* __restrict__ Av,
                                                    const float* __restrict__ Ag,
                                                    const float* __restrict__ Wv,
                                                    const float* __restrict__ Wg,
                                                    float* __restrict__ Cv,
                                                    float* __restrict__ Cg,
                                                    unsigned short* __restrict__ vT) {
    __shared__ __align__(16) char smem[20480];
    const int bid = blockIdx.x;
    const int tid = threadIdx.x;

    if (bid >= 1220) {
        // ---- V transpose: one (b, 64-h slice) per block; grid 64*16 ----
        float* Ts = (float*)smem;  // [49][68] = 13328 B
        const int tb = bid - 1220;
        const int b = tb >> 4;
        const int h0 = (tb & 15) * 64;
        for (int i = tid; i < 49 * 16; i += 256) {
            const int r = i >> 4, hq = i & 15;
            *(float4*)(Ts + r * 68 + hq * 4) =
                *(const float4*)(Av + ((size_t)b * 49 + r) * 1024 + h0 + hq * 4);
        }
        __syncthreads();
        const int h = tid & 63;
        const int grp = tid >> 6;  // r-range grp*16 .. grp*16+15 (octets grp*2, grp*2+1)
        float f[16];
#pragma unroll
        for (int j = 0; j < 16; ++j) {
            const int r = grp * 16 + j;
            f[j] = (r < 49) ? Ts[r * 68 + h] : 0.f;
        }
        const size_t rowbase = ((size_t)b * 1024 + h0 + h) * 64;
#pragma unroll
        for (int o2 = 0; o2 < 2; ++o2) {
            const int o = grp * 2 + o2;
            bf16x8 v = pack8(make_float4(f[o2*8+0], f[o2*8+1], f[o2*8+2], f[o2*8+3]),
                             make_float4(f[o2*8+4], f[o2*8+5], f[o2*8+6], f[o2*8+7]));
            *(bf16x8*)(vT + rowbase + (size_t)((o ^ (h & 7)) * 8)) = v;
        }
        return;
    }

    // ---- GEMM C[m][n] = sum_k A[m][k]*W[n][k], K=1024, N=49->64, M-tile 16 ----
    short* As = (short*)smem;           // [2][16*64]
    short* Ws = (short*)(smem + 4096);  // [2][64*64]
    const float* A; const float* W; float* C; int m0;
    if (bid < 196) { A = Av; W = Wv; C = Cv; m0 = bid * 16; }
    else           { A = Ag; W = Wg; C = Cg; m0 = (bid - 196) * 16; }

    const int wave = tid >> 6, lane = tid & 63;
    const int quad = lane >> 4, l16 = lane & 15;
    const int nb = wave * 16;  // wave's n-quarter

    floatx4 acc = {};

    // staging: A tile 16x64 (1 float4/thread), W tile 64x64 (4 float4/thread)
    const int arow = tid >> 4, ag = tid & 15;
    const int wrow = tid >> 2, wq = tid & 3;
    const float* aptr = A + (size_t)(m0 + arow) * 1024 + ag * 4;
    const bool wvalid = wrow < 49;
    const float* wptr = W + (size_t)wrow * 1024 + wq * 16;
    // LDS store addresses (swizzled; buf stride added at use)
    short* adst = As + arow * 64 + (((ag >> 1) ^ (arow & 7)) * 8) + (ag & 1) * 4;
    short* wdst0 = Ws + wrow * 64;  // octet offsets computed per-store

    float4 ra[2];
    float4 rw[2][4];
    const float4 fz = make_float4(0.f, 0.f, 0.f, 0.f);

    // prologue: chunk 0 -> regs -> LDS buf0; chunk 1 -> regs
    ra[0] = *(const float4*)(aptr);
    if (wvalid) {
        rw[0][0] = *(const float4*)(wptr);
        rw[0][1] = *(const float4*)(wptr + 4);
        rw[0][2] = *(const float4*)(wptr + 8);
        rw[0][3] = *(const float4*)(wptr + 12);
    } else { rw[0][0] = rw[0][1] = rw[0][2] = rw[0][3] = fz; }
    *(bf16x4*)(adst) = pack4(ra[0]);
    *(bf16x8*)(wdst0 + (((wq * 2)     ^ (wrow & 7)) * 8)) = pack8(rw[0][0], rw[0][1]);
    *(bf16x8*)(wdst0 + (((wq * 2 + 1) ^ (wrow & 7)) * 8)) = pack8(rw[0][2], rw[0][3]);
    ra[1] = *(const float4*)(aptr + 64);
    if (wvalid) {
        rw[1][0] = *(const float4*)(wptr + 64);
        rw[1][1] = *(const float4*)(wptr + 68);
        rw[1][2] = *(const float4*)(wptr + 72);
        rw[1][3] = *(const float4*)(wptr + 76);
    } else { rw[1][0] = rw[1][1] = rw[1][2] = rw[1][3] = fz; }
    __syncthreads();

#pragma unroll
    for (int kc = 0; kc < 16; ++kc) {
        const int cur = kc & 1;
        const int curA = cur * 1024, curW = cur * 4096;
        // issue loads for chunk kc+2 into the reg-buffer just freed
        if (kc < 14) {
            const int off = (kc + 2) * 64;
            ra[cur] = *(const float4*)(aptr + off);
            if (wvalid) {
                rw[cur][0] = *(const float4*)(wptr + off);
                rw[cur][1] = *(const float4*)(wptr + off + 4);
                rw[cur][2] = *(const float4*)(wptr + off + 8);
                rw[cur][3] = *(const float4*)(wptr + off + 12);
            }
        }
        // compute on buf[cur]
        {
            const int am = l16;
            const int wn = nb + l16;
            bf16x8 af0 = *(const bf16x8*)(As + curA + am * 64 + ((quad       ^ (am & 7)) * 8));
            bf16x8 af1 = *(const bf16x8*)(As + curA + am * 64 + (((4 + quad) ^ (am & 7)) * 8));
            bf16x8 bf0 = *(const bf16x8*)(Ws + curW + wn * 64 + ((quad       ^ (wn & 7)) * 8));
            bf16x8 bf1 = *(const bf16x8*)(Ws + curW + wn * 64 + (((4 + quad) ^ (wn & 7)) * 8));
            acc = __builtin_amdgcn_mfma_f32_16x16x32_bf16(af0, bf0, acc, 0, 0, 0);
            acc = __builtin_amdgcn_mfma_f32_16x16x32_bf16(af1, bf1, acc, 0, 0, 0);
        }
        // store chunk kc+1 into the other buffer
        if (kc < 15) {
            const int nxt = cur ^ 1;
            const int nA = nxt * 1024, nW = nxt * 4096;
            *(bf16x4*)(adst + nA) = pack4(ra[nxt]);
            *(bf16x8*)(wdst0 + nW + (((wq * 2)     ^ (wrow & 7)) * 8)) = pack8(rw[nxt][0], rw[nxt][1]);
            *(bf16x8*)(wdst0 + nW + (((wq * 2 + 1) ^ (wrow & 7)) * 8)) = pack8(rw[nxt][2], rw[nxt][3]);
        }
        __syncthreads();
    }

    const int n = nb + l16;
    if (n < 49) {
#pragma unroll
        for (int r = 0; r < 4; ++r) {
            const int m = m0 + quad * 4 + r;
            C[(size_t)m * 49 + n] = acc[r];
        }
    }
}

// z[b,t,r] = sum_k tanh(cv[b,r,k]+cg[b,t,k])*Wh[k]; alpha = softmax_r(z).
// Writes fp32 alpha to d_out and bf16 swizzled padded alpha16 to ws.
__global__ __launch_bounds__(256) void zsoftmax(const float* __restrict__ cv,
                                                const float* __restrict__ cg,
                                                const float* __restrict__ Wh,
                                                float* __restrict__ alpha,
                                                unsigned short* __restrict__ a16) {
    const int b = blockIdx.x >> 4;
    const int t0 = (blockIdx.x & 15) * 16;
    __shared__ __align__(16) float cvl[49 * 52];
    __shared__ __align__(16) float cgl[16 * 52];
    __shared__ __align__(16) float whl[52];

    const int tid = threadIdx.x;
    for (int i = tid; i < 49 * 49; i += 256) {
        int r = i / 49, k = i - r * 49;
        cvl[r * 52 + k] = cv[(size_t)b * 2401 + i];
    }
    for (int i = tid; i < 16 * 49; i += 256) {
        int t = i / 49, k = i - t * 49;
        cgl[t * 52 + k] = cg[((size_t)b * 256 + t0) * 49 + i];
    }
    if (tid < 52) whl[tid] = (tid < 49) ? Wh[tid] : 0.f;
    __syncthreads();

    const int wave = tid >> 6;
    const int lane = tid & 63;
    const float4* cvr = (const float4*)(cvl + lane * 52);
    const float4* wh4 = (const float4*)whl;

    for (int i = 0; i < 4; ++i) {
        const int tl = wave * 4 + i;
        float z = -INFINITY;
        if (lane < 49) {
            const float4* cgr = (const float4*)(cgl + tl * 52);
            float s = 0.f;
#pragma unroll 4
            for (int kk = 0; kk < 12; ++kk) {
                float4 x = cvr[kk], g = cgr[kk], w = wh4[kk];
                float r0 = __builtin_amdgcn_rcpf(__expf(2.f * (x.x + g.x)) + 1.f);
                float r1 = __builtin_amdgcn_rcpf(__expf(2.f * (x.y + g.y)) + 1.f);
                float r2 = __builtin_amdgcn_rcpf(__expf(2.f * (x.z + g.z)) + 1.f);
                float r3 = __builtin_amdgcn_rcpf(__expf(2.f * (x.w + g.w)) + 1.f);
                s = fmaf(1.f - 2.f * r0, w.x, s);
                s = fmaf(1.f - 2.f * r1, w.y, s);
                s = fmaf(1.f - 2.f * r2, w.z, s);
                s = fmaf(1.f - 2.f * r3, w.w, s);
            }
            {
                float x = cvl[lane * 52 + 48] + cgl[tl * 52 + 48];
                float r0 = __builtin_amdgcn_rcpf(__expf(2.f * x) + 1.f);
                s = fmaf(1.f - 2.f * r0, whl[48], s);
            }
            z = s;
        }
        float m = z;
        for (int off = 32; off; off >>= 1) m = fmaxf(m, __shfl_xor(m, off));
        float p = (lane < 49) ? __expf(z - m) : 0.f;
        float sum = p;
        for (int off = 32; off; off >>= 1) sum += __shfl_xor(sum, off);
        const float val = p * __builtin_amdgcn_rcpf(sum);  // 0 for lane>=49

        const size_t grow = (size_t)b * 256 + t0 + tl;
        if (lane < 49) alpha[grow * 49 + lane] = val;
        const int pos = (((lane >> 3) ^ (tl & 7)) << 3) | (lane & 7);
        a16[grow * 64 + pos] = f2bf_bits(val);
    }
}

// c_t[b,t,h] = sum_r alpha[b,t,r] * V[b,r,h] via bf16 MFMA (K=49 padded 64).
__global__ __launch_bounds__(256) void ct_mfma(const unsigned short* __restrict__ a16,
                                               const unsigned short* __restrict__ vT,
                                               float* __restrict__ C) {
    const int bid = blockIdx.x;
    const int b = bid >> 5;
    const int t0 = ((bid >> 3) & 3) * 64;
    const int h0 = (bid & 7) * 128;

    __shared__ __align__(16) short Al[64 * 64];   // [t][r] bf16, swizzled
    __shared__ __align__(16) short Vl[128 * 64];  // [h][r] bf16, swizzled

    const int tid = threadIdx.x;
    {
        const bf16x8* src = (const bf16x8*)(a16 + ((size_t)b * 256 + t0) * 64);
        bf16x8* dst = (bf16x8*)Al;
#pragma unroll
        for (int p = 0; p < 2; ++p) dst[tid + p * 256] = src[tid + p * 256];
    }
    {
        const bf16x8* src = (const bf16x8*)(vT + ((size_t)b * 1024 + h0) * 64);
        bf16x8* dst = (bf16x8*)Vl;
#pragma unroll
        for (int p = 0; p < 4; ++p) dst[tid + p * 256] = src[tid + p * 256];
    }
    __syncthreads();

    const int wave = tid >> 6, lane = tid & 63;
    const int quad = lane >> 4, l16 = lane & 15;
    const int tb = (wave & 1) * 32;
    const int hb = (wave >> 1) * 64;

    floatx4 acc[2][4] = {};
#pragma unroll
    for (int kc = 0; kc < 2; ++kc) {
        bf16x8 af[2];
#pragma unroll
        for (int ms = 0; ms < 2; ++ms) {
            const int row = tb + ms * 16 + l16;
            af[ms] = *(const bf16x8*)(Al + row * 64 + (((kc << 2) + quad) ^ (row & 7)) * 8);
        }
#pragma unroll
        for (int ns = 0; ns < 4; ++ns) {
            const int row = hb + ns * 16 + l16;
            bf16x8 bf = *(const bf16x8*)(Vl + row * 64 + (((kc << 2) + quad) ^ (row & 7)) * 8);
#pragma unroll
            for (int ms = 0; ms < 2; ++ms)
                acc[ms][ns] = __builtin_amdgcn_mfma_f32_16x16x32_bf16(af[ms], bf, acc[ms][ns], 0, 0, 0);
        }
    }

#pragma unroll
    for (int ms = 0; ms < 2; ++ms) {
        const int t = t0 + tb + ms * 16 + quad * 4;
#pragma unroll
        for (int ns = 0; ns < 4; ++ns) {
            const int h = h0 + hb + ns * 16 + l16;
#pragma unroll
            for (int r = 0; r < 4; ++r)
                C[((size_t)b * 256 + t + r) * 1024 + h] = acc[ms][ns][r];
        }
    }
}

extern "C" void kernel_launch(void* const* d_in, const int* in_sizes, int n_in,
                              void* d_out, int out_size, void* d_ws, size_t ws_size,
                              hipStream_t stream) {
    const float* V   = (const float*)d_in[0];
    const float* h_t = (const float*)d_in[1];
    const float* Wv  = (const float*)d_in[2];
    const float* Wg  = (const float*)d_in[3];
    const float* Wh  = (const float*)d_in[4];

    float* c_t   = (float*)d_out;
    float* alpha = (float*)d_out + 16777216;

    float* cv = (float*)d_ws;                                        // 153664 f
    float* cg = cv + 153664;                                         // 802816 f
    unsigned short* a16 = (unsigned short*)((char*)d_ws + 3825920);  // 16384*64
    unsigned short* vT  = a16 + 16384 * 64;                          // 64*1024*64

    gemm_mfma_tr<<<196 + 1024 + 1024, 256, 0, stream>>>(V, h_t, Wv, Wg, cv, cg, vT);
    zsoftmax<<<1024, 256, 0, stream>>>(cv, cg, Wh, alpha, a16);
    ct_mfma<<<2048, 256, 0, stream>>>(a16, vT, c_t);
}